// Round 4
// baseline (172.218 us; speedup 1.0000x reference)
//
#include <hip/hip_runtime.h>
#include <hip/hip_bf16.h>
#include <math.h>

// Problem constants (from reference)
#define INPUT_DIM 30000
#define UNITS     2048
#define NNZ       500000
#define BATCH     32

// ---------------------------------------------------------------------------
// Kernel 1: transpose x [32][30000] -> xt [30000][32], LDS-tiled so BOTH the
// global reads and writes are coalesced (old version gathered 64 distinct
// lines per wave instruction). Tile: 64 i x 32 b per 256-thread block.
// ---------------------------------------------------------------------------
__global__ __launch_bounds__(256) void transpose_k(const float* __restrict__ x,
                                                   float* __restrict__ xt) {
    __shared__ float tile[32][65];                // +1 pad: conflict-free
    const int i0 = blockIdx.x * 64;
    const int t  = threadIdx.x;
    const int w  = t >> 6;                        // wave 0..3
    const int l  = t & 63;                        // lane
    const bool iok = (i0 + l) < INPUT_DIM;
    #pragma unroll
    for (int bb = 0; bb < 8; ++bb) {              // 8 batch rows per wave
        int b = w * 8 + bb;
        tile[b][l] = iok ? x[b * INPUT_DIM + i0 + l] : 0.f;
    }
    __syncthreads();
    float4* __restrict__ xt4 = (float4*)xt;
    #pragma unroll
    for (int rep = 0; rep < 2; ++rep) {
        int f  = t + rep * 256;                   // 0..511 float4 slots
        int il = f >> 3;                          // local i 0..63
        int b4 = f & 7;                           // batch quad 0..7
        if (i0 + il < INPUT_DIM)
            xt4[(size_t)(i0 + il) * 8 + b4] =
                make_float4(tile[b4 * 4 + 0][il], tile[b4 * 4 + 1][il],
                            tile[b4 * 4 + 2][il], tile[b4 * 4 + 3][il]);
    }
}

// ---------------------------------------------------------------------------
// Kernel 2: scatter-accumulate. grid (nchunk=64, 4 batch groups), 1024 thr.
// Straight-line 8-entry rounds: ALL idx/kv loads issued first into register
// arrays (16 independent loads in flight), then xt gathers with 1-ahead
// prefetch, then swizzled LDS atomics. OOB slots load row=col=0, v=0 ->
// harmless zero-adds, no divergence in the compute phase.
// LDS slot swizzle (c+j)&7 spreads the 8 sequential ds_adds over all 32
// banks. acc[c*8 + s] holds batch (s-c)&7 of the group.
// ---------------------------------------------------------------------------
__global__ __launch_bounds__(1024) void scatter_k(const int* __restrict__ idx,
                                                  const float* __restrict__ kv,
                                                  const float* __restrict__ xt,
                                                  float* __restrict__ part,
                                                  int nchunk) {
    __shared__ float acc[UNITS * 8];              // 64 KB

    const int chunk = blockIdx.x;
    const int bg    = blockIdx.y;

    {
        float4* a4 = (float4*)acc;
        #pragma unroll
        for (int t = threadIdx.x; t < UNITS * 2; t += 1024)
            a4[t] = make_float4(0.f, 0.f, 0.f, 0.f);
    }
    __syncthreads();

    // int64 vs int32 index detection (uniform): int64 LE -> high words zero.
    const bool is64 = ((idx[3] | idx[5] | idx[7]) == 0);

    const int e0   = (int)((long long)NNZ * chunk / nchunk);
    const int e1   = (int)((long long)NNZ * (chunk + 1) / nchunk);
    const int boff = bg * 8;

    for (int eb = e0; eb < e1; eb += 8 * 1024) {
        int   rows[8], cols[8];
        float vals[8];
        // phase 1: stream idx+kv into registers (16 independent loads)
        if (is64) {
            const int4* __restrict__ p = (const int4*)idx;
            #pragma unroll
            for (int k = 0; k < 8; ++k) {
                int e = eb + k * 1024 + threadIdx.x;
                bool ok = e < e1;
                int4  q = ok ? p[e] : make_int4(0, 0, 0, 0);
                vals[k] = ok ? kv[e] : 0.f;
                rows[k] = q.x;
                cols[k] = q.z;
            }
        } else {
            const int2* __restrict__ p = (const int2*)idx;
            #pragma unroll
            for (int k = 0; k < 8; ++k) {
                int e = eb + k * 1024 + threadIdx.x;
                bool ok = e < e1;
                int2  q = ok ? p[e] : make_int2(0, 0);
                vals[k] = ok ? kv[e] : 0.f;
                rows[k] = q.x;
                cols[k] = q.y;
            }
        }
        // phase 2: gather xt (1-ahead prefetch) + swizzled LDS atomics
        const float4* __restrict__ xr0 = (const float4*)(xt + rows[0] * 32 + boff);
        float4 cx0 = xr0[0];
        float4 cx1 = xr0[1];
        #pragma unroll
        for (int k = 0; k < 8; ++k) {
            float4 nx0, nx1;
            if (k + 1 < 8) {
                const float4* __restrict__ xr =
                    (const float4*)(xt + rows[k + 1] * 32 + boff);
                nx0 = xr[0];
                nx1 = xr[1];
            }
            float* __restrict__ base = acc + cols[k] * 8;
            const int   sw = cols[k] & 7;
            const float v  = vals[k];
            atomicAdd(base + ((sw + 0) & 7), v * cx0.x);
            atomicAdd(base + ((sw + 1) & 7), v * cx0.y);
            atomicAdd(base + ((sw + 2) & 7), v * cx0.z);
            atomicAdd(base + ((sw + 3) & 7), v * cx0.w);
            atomicAdd(base + ((sw + 4) & 7), v * cx1.x);
            atomicAdd(base + ((sw + 5) & 7), v * cx1.y);
            atomicAdd(base + ((sw + 6) & 7), v * cx1.z);
            atomicAdd(base + ((sw + 7) & 7), v * cx1.w);
            if (k + 1 < 8) { cx0 = nx0; cx1 = nx1; }
        }
    }
    __syncthreads();

    float4* __restrict__ dst =
        (float4*)(part + (size_t)(bg * nchunk + chunk) * (UNITS * 8));
    const float4* __restrict__ src = (const float4*)acc;
    #pragma unroll
    for (int t = threadIdx.x; t < UNITS * 2; t += 1024) dst[t] = src[t];
}

// ---------------------------------------------------------------------------
// Kernel 3: reduce partials, un-swizzle, bias, tanh. grid (16,4) x 1024 thr.
// 4-way chunk split per float4-slot (sub = t&3 sums nchunk/4 chunks), LDS
// combine, then 4 scattered output stores per active thread.
// ---------------------------------------------------------------------------
__global__ __launch_bounds__(1024) void reduce_k(const float* __restrict__ part,
                                                 const float* __restrict__ bias,
                                                 float* __restrict__ out,
                                                 int nchunk) {
    __shared__ float4 red[1024];                  // [sub][slotL]
    const int bg    = blockIdx.y;
    const int t     = threadIdx.x;
    const int slotL = t >> 2;
    const int sub   = t & 3;
    const int slot  = blockIdx.x * 256 + slotL;   // float4 slot 0..4095
    const int ksub  = nchunk >> 2;

    const float4* __restrict__ p =
        (const float4*)(part + (size_t)bg * nchunk * (UNITS * 8)) +
        slot + (size_t)sub * ksub * (UNITS * 2);
    float4 s = make_float4(0.f, 0.f, 0.f, 0.f);
    #pragma unroll 8
    for (int k = 0; k < ksub; ++k) {
        float4 q = p[(size_t)k * (UNITS * 2)];
        s.x += q.x; s.y += q.y; s.z += q.z; s.w += q.w;
    }
    red[sub * 256 + slotL] = s;
    __syncthreads();

    if (sub == 0) {
        float4 a = red[slotL];
        float4 b = red[256 + slotL];
        float4 c4 = red[512 + slotL];
        float4 d = red[768 + slotL];
        float sx = a.x + b.x + c4.x + d.x;
        float sy = a.y + b.y + c4.y + d.y;
        float sz = a.z + b.z + c4.z + d.z;
        float sw4 = a.w + b.w + c4.w + d.w;

        const int f  = slot * 4;                  // slab element index
        const int s0 = f & 7;                     // 0 or 4
        const int c  = f >> 3;
        const float bs = bias[c];
        const int   sw = c & 7;
        const int   b0 = bg * 8;
        out[(b0 + ((s0 + 0 - sw) & 7)) * UNITS + c] = tanhf(sx + bs);
        out[(b0 + ((s0 + 1 - sw) & 7)) * UNITS + c] = tanhf(sy + bs);
        out[(b0 + ((s0 + 2 - sw) & 7)) * UNITS + c] = tanhf(sz + bs);
        out[(b0 + ((s0 + 3 - sw) & 7)) * UNITS + c] = tanhf(sw4 + bs);
    }
}

// ---------------------------------------------------------------------------
extern "C" void kernel_launch(void* const* d_in, const int* in_sizes, int n_in,
                              void* d_out, int out_size, void* d_ws, size_t ws_size,
                              hipStream_t stream) {
    const float* x    = (const float*)d_in[0];
    const float* kv   = (const float*)d_in[1];
    const float* bias = (const float*)d_in[2];
    const int*   idx  = (const int*)d_in[3];
    float*       out  = (float*)d_out;

    const size_t xt_bytes = (size_t)INPUT_DIM * BATCH * sizeof(float); // 3.84 MB
    float* xt = (float*)d_ws;

    // largest chunk count whose partial buffer fits the workspace
    // (slab = 64 KB per (chunk, batch-group); 4 groups; multiples of 4 only)
    int nchunk = 4;
    const int cand[] = {64, 32, 16, 8, 4};
    for (int i = 0; i < 5; ++i) {
        size_t need = xt_bytes + (size_t)cand[i] * 4 * (UNITS * 8) * sizeof(float);
        if (need <= ws_size) { nchunk = cand[i]; break; }
    }
    float* part = (float*)((char*)d_ws + xt_bytes);

    transpose_k<<<(INPUT_DIM + 63) / 64, 256, 0, stream>>>(x, xt);
    scatter_k<<<dim3(nchunk, 4), 1024, 0, stream>>>(idx, kv, xt, part, nchunk);
    reduce_k<<<dim3(16, 4), 1024, 0, stream>>>(part, bias, out, nchunk);
}

// Round 5
// 83.022 us; speedup vs baseline: 2.0744x; 2.0744x over previous
//
#include <hip/hip_runtime.h>
#include <hip/hip_bf16.h>
#include <math.h>

// Problem constants (from reference)
#define INPUT_DIM 30000
#define UNITS     2048
#define NNZ       500000
#define BATCH     32

// ---------------------------------------------------------------------------
// Kernel 1: transpose x [32][30000] -> xt [30000][32] (LDS-tiled, coalesced
// both sides) + zero the ws2/spill accumulator arrays (131072 floats).
// ---------------------------------------------------------------------------
__global__ __launch_bounds__(256) void transpose_k(const float* __restrict__ x,
                                                   float* __restrict__ xt,
                                                   float4* __restrict__ zero4) {
    // zero ws2 + spill: 32768 float4
    {
        int g = blockIdx.x * 256 + threadIdx.x;
        if (g < 32768) zero4[g] = make_float4(0.f, 0.f, 0.f, 0.f);
    }
    __shared__ float tile[32][65];                // +1 pad: conflict-free
    const int i0 = blockIdx.x * 64;
    const int t  = threadIdx.x;
    const int w  = t >> 6;                        // wave 0..3
    const int l  = t & 63;                        // lane
    const bool iok = (i0 + l) < INPUT_DIM;
    #pragma unroll
    for (int bb = 0; bb < 8; ++bb) {              // 8 batch rows per wave
        int b = w * 8 + bb;
        tile[b][l] = iok ? x[b * INPUT_DIM + i0 + l] : 0.f;
    }
    __syncthreads();
    float4* __restrict__ xt4 = (float4*)xt;
    #pragma unroll
    for (int rep = 0; rep < 2; ++rep) {
        int f  = t + rep * 256;                   // 0..511 float4 slots
        int il = f >> 3;                          // local i 0..63
        int b4 = f & 7;                           // batch quad 0..7
        if (i0 + il < INPUT_DIM)
            xt4[(size_t)(i0 + il) * 8 + b4] =
                make_float4(tile[b4 * 4 + 0][il], tile[b4 * 4 + 1][il],
                            tile[b4 * 4 + 2][il], tile[b4 * 4 + 3][il]);
    }
}

// ---------------------------------------------------------------------------
// Kernel 2: residue-sliced scatter with REGISTER accumulation (no LDS atomics
// — R1-R4 post-mortem: 16M LDS atomic RMWs @ ~3.5 cy/lane-op were the 90 µs
// invariant wall). Entries n = r + 2048*m share one column in this dataset;
// each thread owns (residue r, batch-group bg, entry-stripe es) and sums its
// ~8 entries into 8 registers. col0 is LOADED from idx (entry n=r); any entry
// whose col != col0 takes a global-atomic spill path (never, for this data)
// -> correct for arbitrary indices, atomic-free for the actual ones.
// Grid: 512 WGs x 512 thr; thread = (rl 0..3, bg 0..3, es 0..31).
// ---------------------------------------------------------------------------
__global__ __launch_bounds__(512) void scatter_k(const int* __restrict__ idx,
                                                 const float* __restrict__ kv,
                                                 const float* __restrict__ xt,
                                                 float* __restrict__ ws2,
                                                 float* __restrict__ spill) {
    __shared__ float part[32 * 128];              // [es][b 0..31][rl 0..3]
    __shared__ int   colA[4];

    const int t    = threadIdx.x;
    const int rl   = t & 3;
    const int bg   = (t >> 2) & 3;
    const int es   = t >> 4;                      // 0..31
    const int r    = blockIdx.x * 4 + rl;         // residue 0..2047
    const int boff = bg * 8;

    // int64 vs int32 index detection (uniform): int64 LE -> high words zero.
    const bool is64 = ((idx[3] | idx[5] | idx[7]) == 0);
    const int  col0 = is64 ? idx[4 * r + 2] : idx[2 * r + 1];

    float acc[8];
    #pragma unroll
    for (int k = 0; k < 8; ++k) acc[k] = 0.f;

    const int step = UNITS * 32;                  // 65536: per-thread stride
    for (int n0 = r + UNITS * es; n0 < NNZ; n0 += 4 * step) {
        int rows[4], cols[4];
        float vals[4];
        if (is64) {
            const int4* __restrict__ p = (const int4*)idx;
            #pragma unroll
            for (int k = 0; k < 4; ++k) {
                int e = n0 + k * step;
                bool ok = e < NNZ;
                int4 q = ok ? p[e] : make_int4(0, 0, col0, 0);
                rows[k] = q.x; cols[k] = q.z;
                vals[k] = ok ? kv[e] : 0.f;
            }
        } else {
            const int2* __restrict__ p = (const int2*)idx;
            #pragma unroll
            for (int k = 0; k < 4; ++k) {
                int e = n0 + k * step;
                bool ok = e < NNZ;
                int2 q = ok ? p[e] : make_int2(0, col0);
                rows[k] = q.x; cols[k] = q.y;
                vals[k] = ok ? kv[e] : 0.f;
            }
        }
        // all 8 gathers issued independently (32B contiguous per lane; the 4
        // bg-threads of an entry jointly cover its full 128B xt row)
        float4 g0[4], g1[4];
        #pragma unroll
        for (int k = 0; k < 4; ++k) {
            const float4* __restrict__ xr = (const float4*)(xt + rows[k] * 32 + boff);
            g0[k] = xr[0];
            g1[k] = xr[1];
        }
        #pragma unroll
        for (int k = 0; k < 4; ++k) {
            float v = vals[k];
            if (cols[k] == col0) {                // uniformly true for this data
                acc[0] += v * g0[k].x; acc[1] += v * g0[k].y;
                acc[2] += v * g0[k].z; acc[3] += v * g0[k].w;
                acc[4] += v * g1[k].x; acc[5] += v * g1[k].y;
                acc[6] += v * g1[k].z; acc[7] += v * g1[k].w;
            } else {                              // correctness fallback
                float* __restrict__ sp = spill + cols[k];
                atomicAdd(sp + (boff + 0) * UNITS, v * g0[k].x);
                atomicAdd(sp + (boff + 1) * UNITS, v * g0[k].y);
                atomicAdd(sp + (boff + 2) * UNITS, v * g0[k].z);
                atomicAdd(sp + (boff + 3) * UNITS, v * g0[k].w);
                atomicAdd(sp + (boff + 4) * UNITS, v * g1[k].x);
                atomicAdd(sp + (boff + 5) * UNITS, v * g1[k].y);
                atomicAdd(sp + (boff + 6) * UNITS, v * g1[k].z);
                atomicAdd(sp + (boff + 7) * UNITS, v * g1[k].w);
            }
        }
    }

    // combine 32 es-stripes via plain LDS writes (one-time; conflicts cheap)
    #pragma unroll
    for (int bb = 0; bb < 8; ++bb)
        part[es * 128 + (boff + bb) * 4 + rl] = acc[bb];
    if (t < 4) colA[t] = col0;
    __syncthreads();

    if (t < 128) {
        const int rr = t & 3;
        const int b  = t >> 2;                    // 0..31
        float s = 0.f;
        #pragma unroll
        for (int e = 0; e < 32; ++e) s += part[e * 128 + b * 4 + rr];
        // one atomic per (b, col); distinct addrs when cols are bijective
        atomicAdd(&ws2[b * UNITS + colA[rr]], s);
    }
}

// ---------------------------------------------------------------------------
// Kernel 3: out = tanh(ws2 + spill + bias), fully coalesced. 65536 elements.
// ---------------------------------------------------------------------------
__global__ __launch_bounds__(256) void final_k(const float* __restrict__ ws2,
                                               const float* __restrict__ spill,
                                               const float* __restrict__ bias,
                                               float* __restrict__ out) {
    int tid = blockIdx.x * 256 + threadIdx.x;     // 0..65535
    int c   = tid & (UNITS - 1);
    out[tid] = tanhf(ws2[tid] + spill[tid] + bias[c]);
}

// ---------------------------------------------------------------------------
extern "C" void kernel_launch(void* const* d_in, const int* in_sizes, int n_in,
                              void* d_out, int out_size, void* d_ws, size_t ws_size,
                              hipStream_t stream) {
    const float* x    = (const float*)d_in[0];
    const float* kv   = (const float*)d_in[1];
    const float* bias = (const float*)d_in[2];
    const int*   idx  = (const int*)d_in[3];
    float*       out  = (float*)d_out;

    // workspace layout: xt [960000 f] | ws2 [65536 f] | spill [65536 f]
    float* xt    = (float*)d_ws;
    float* ws2   = xt + (size_t)INPUT_DIM * BATCH;
    float* spill = ws2 + BATCH * UNITS;

    transpose_k<<<(INPUT_DIM + 63) / 64, 256, 0, stream>>>(x, xt, (float4*)ws2);
    scatter_k<<<UNITS / 4, 512, 0, stream>>>(idx, kv, xt, ws2, spill);
    final_k<<<(BATCH * UNITS) / 256, 256, 0, stream>>>(ws2, spill, bias, out);
}